// Round 1
// baseline (228.319 us; speedup 1.0000x reference)
//
#include <hip/hip_runtime.h>

#define Bn 8
#define Tn 1024
#define Fn 512
#define Hn 8
#define DKn 64
#define Pn 2047

namespace {

typedef _Float16 h8 __attribute__((ext_vector_type(8)));
typedef float f4 __attribute__((ext_vector_type(4)));

__device__ __forceinline__ unsigned short f2h(float f) {
  _Float16 h = (_Float16)f;
  return __builtin_bit_cast(unsigned short, h);
}

__device__ __forceinline__ f4 mfma16(h8 a, h8 b, f4 c) {
  return __builtin_amdgcn_mfma_f32_16x16x32_f16(a, b, c, 0, 0, 0);
}

// Read a 16B MFMA fragment from a swizzled LDS tile with 128B rows.
// row: tile row; kk: K-dim 32-elem block; grp: lane>>4.
__device__ __forceinline__ h8 frag_ld(const unsigned char* p, int row, int kk, int grp) {
  int off = row * 128 + kk * 64 + grp * 16;
  off ^= (row & 7) << 4;
  return *(const h8*)(p + off);
}

// ---------------- mask dtype detection (bool bytes vs int32) ----------------
__global__ void detect_kernel(const unsigned int* m, int* flag) {
  if (threadIdx.x == 0) {
    int bm = 0;
    for (int i = 0; i < 256; ++i)
      if (m[i] > 1u) bm = 1;
    *flag = bm;  // 1 => byte mask, 0 => int32 mask
  }
}

// ---------------- projection GEMM: C = A @ W^T (+bias), scattered epilogue --
// MODE 0: Q -> writes Qu=q+u, Qv=q+v   [b][h][t][d] fp16
// MODE 1: K -> writes K               [b][h][t][d] fp16
// MODE 2: V -> writes V transposed    [b][h][d][t] fp16
// MODE 3: pos -> writes P             [h][p][d]    fp16 (no bias)
// MODE 4: out -> A is fp16 x, writes f32 out [m][n]
template <int MODE>
__global__ __launch_bounds__(256) void proj_kernel(
    const float* __restrict__ Af, const unsigned short* __restrict__ Ah,
    const float* __restrict__ W, const float* __restrict__ bias,
    const float* __restrict__ pbu, const float* __restrict__ pbv,
    unsigned short* __restrict__ o0, unsigned short* __restrict__ o1,
    float* __restrict__ ofp, int M) {
  __shared__ __align__(16) unsigned char sA[64 * 128];
  __shared__ __align__(16) unsigned char sB[64 * 128];

  const int t = threadIdx.x;
  const int w = t >> 6, l = t & 63;
  const int grp = l >> 4, lc = l & 15;
  const int m0 = blockIdx.x * 64, n0 = blockIdx.y * 64;
  const int srow = t >> 2, sseg = t & 3;

  f4 acc[4];
#pragma unroll
  for (int c = 0; c < 4; ++c) acc[c] = {0.f, 0.f, 0.f, 0.f};

  for (int kt = 0; kt < 8; ++kt) {
    // ---- stage A tile (64x64) ----
    {
      int gm = m0 + srow;
      int sw = (srow & 7) << 4;
      if (MODE == 4) {
        const unsigned short* ar = Ah + (size_t)gm * Fn + kt * 64 + sseg * 16;
#pragma unroll
        for (int hh = 0; hh < 2; ++hh) {
          uint4 qd = *(const uint4*)(ar + hh * 8);
          int off = srow * 128 + sseg * 32 + hh * 16;
          *(uint2*)(sA + ((off) ^ sw)) = make_uint2(qd.x, qd.y);
          *(uint2*)(sA + ((off + 8) ^ sw)) = make_uint2(qd.z, qd.w);
        }
      } else {
        bool valid = (gm < M);
        const float* ar = Af + (size_t)gm * Fn + kt * 64 + sseg * 16;
#pragma unroll
        for (int i = 0; i < 4; ++i) {
          float4 fv = valid ? *(const float4*)(ar + 4 * i) : make_float4(0.f, 0.f, 0.f, 0.f);
          uint2 pk;
          pk.x = (unsigned)f2h(fv.x) | ((unsigned)f2h(fv.y) << 16);
          pk.y = (unsigned)f2h(fv.z) | ((unsigned)f2h(fv.w) << 16);
          int off = srow * 128 + sseg * 32 + i * 8;
          *(uint2*)(sA + (off ^ sw)) = pk;
        }
      }
      // ---- stage B tile: W rows n0..n0+63 ----
      const float* br = W + (size_t)(n0 + srow) * Fn + kt * 64 + sseg * 16;
#pragma unroll
      for (int i = 0; i < 4; ++i) {
        float4 fv = *(const float4*)(br + 4 * i);
        uint2 pk;
        pk.x = (unsigned)f2h(fv.x) | ((unsigned)f2h(fv.y) << 16);
        pk.y = (unsigned)f2h(fv.z) | ((unsigned)f2h(fv.w) << 16);
        int off = srow * 128 + sseg * 32 + i * 8;
        *(uint2*)(sB + (off ^ sw)) = pk;
      }
    }
    __syncthreads();
    const int arow = 16 * w + lc;
    h8 a0 = frag_ld(sA, arow, 0, grp);
    h8 a1 = frag_ld(sA, arow, 1, grp);
#pragma unroll
    for (int c = 0; c < 4; ++c) {
      int brow = 16 * c + lc;
      acc[c] = mfma16(a0, frag_ld(sB, brow, 0, grp), acc[c]);
      acc[c] = mfma16(a1, frag_ld(sB, brow, 1, grp), acc[c]);
    }
    __syncthreads();
  }

  // ---- epilogue ----
#pragma unroll
  for (int c = 0; c < 4; ++c) {
#pragma unroll
    for (int r = 0; r < 4; ++r) {
      int m = m0 + 16 * w + grp * 4 + r;
      int n = n0 + 16 * c + lc;
      float vv = acc[c][r];
      if (MODE == 0) {
        vv += bias[n];
        int b = m >> 10, tt = m & 1023, h = n >> 6, d = n & 63;
        size_t qi = ((size_t)(b * Hn + h) * Tn + tt) * DKn + d;
        o0[qi] = f2h(vv + pbu[n]);
        o1[qi] = f2h(vv + pbv[n]);
      } else if (MODE == 1) {
        vv += bias[n];
        int b = m >> 10, tt = m & 1023, h = n >> 6, d = n & 63;
        o0[((size_t)(b * Hn + h) * Tn + tt) * DKn + d] = f2h(vv);
      } else if (MODE == 2) {
        vv += bias[n];
        int b = m >> 10, tt = m & 1023, h = n >> 6, d = n & 63;
        o0[((size_t)(b * Hn + h) * DKn + d) * Tn + tt] = f2h(vv);
      } else if (MODE == 3) {
        if (m < M) {
          int h = n >> 6, d = n & 63;
          o0[((size_t)h * Pn + m) * DKn + d] = f2h(vv);
        }
      } else {
        ofp[(size_t)m * Fn + n] = vv + bias[n];
      }
    }
  }
}

// ---------------- fused rel-pos flash attention ----------------
__global__ __launch_bounds__(256) void attn_kernel(
    const unsigned short* __restrict__ Qu, const unsigned short* __restrict__ Qv,
    const unsigned short* __restrict__ Kb, const unsigned short* __restrict__ Vt,
    const unsigned short* __restrict__ Pb, const void* __restrict__ maskp,
    const int* __restrict__ flagp, unsigned short* __restrict__ xb) {
  __shared__ __align__(16) unsigned char sK[64 * 128];   // K tile [key][d]
  __shared__ __align__(16) unsigned char sV[64 * 128];   // V tile [d][key]
  __shared__ __align__(16) unsigned char sP[128 * 128];  // pos window [p'][d]
  __shared__ __align__(16) unsigned char sM[64 * 64];    // mask bytes [q][k]
  __shared__ float sBD[64 * 129];                        // BD' f32 [q][p']
  __shared__ __align__(16) unsigned char sPp[64 * 128];  // P fp16 [q][key]

  const int t = threadIdx.x;
  const int w = t >> 6, l = t & 63;
  const int grp = l >> 4, lc = l & 15;
  const int q0 = blockIdx.x * 64;
  const int bh = blockIdx.y;
  const int b = bh >> 3, h = bh & 7;
  const int byte_mode = *flagp;

  // preload Q fragments (this wave's 16 q-rows)
  h8 au[2], av[2];
  {
    const size_t qbase = ((size_t)bh * Tn + q0 + 16 * w + lc) * DKn;
#pragma unroll
    for (int kk = 0; kk < 2; ++kk) {
      au[kk] = *(const h8*)(Qu + qbase + kk * 32 + grp * 8);
      av[kk] = *(const h8*)(Qv + qbase + kk * 32 + grp * 8);
    }
  }

  float m_run[4], l_run[4];
  f4 oacc[4];
#pragma unroll
  for (int r = 0; r < 4; ++r) { m_run[r] = -1e30f; l_run[r] = 0.f; }
#pragma unroll
  for (int c = 0; c < 4; ++c) oacc[c] = {0.f, 0.f, 0.f, 0.f};

  const size_t kvbase = (size_t)bh * Tn * DKn;

  for (int kt = 0; kt < 16; ++kt) {
    const int k0 = kt * 64;
    const int pbase = k0 - q0 + 960;

    __syncthreads();
    // ---- stage K, V, mask, pos-window ----
    {
      int row = t >> 2, seg = t & 3;
      int sw = (row & 7) << 4;
      {
        const unsigned short* src = Kb + kvbase + (size_t)(k0 + row) * DKn + seg * 16;
#pragma unroll
        for (int hh = 0; hh < 2; ++hh) {
          uint4 qd = *(const uint4*)(src + hh * 8);
          int off = row * 128 + seg * 32 + hh * 16;
          *(uint2*)(sK + ((off) ^ sw)) = make_uint2(qd.x, qd.y);
          *(uint2*)(sK + ((off + 8) ^ sw)) = make_uint2(qd.z, qd.w);
        }
      }
      {
        const unsigned short* src = Vt + kvbase + (size_t)row * Tn + k0 + seg * 16;
#pragma unroll
        for (int hh = 0; hh < 2; ++hh) {
          uint4 qd = *(const uint4*)(src + hh * 8);
          int off = row * 128 + seg * 32 + hh * 16;
          *(uint2*)(sV + ((off) ^ sw)) = make_uint2(qd.x, qd.y);
          *(uint2*)(sV + ((off + 8) ^ sw)) = make_uint2(qd.z, qd.w);
        }
      }
      if (byte_mode) {
        const unsigned char* mb = (const unsigned char*)maskp + (size_t)b * Tn * Tn +
                                  (size_t)(q0 + row) * Tn + k0 + seg * 16;
        *(uint4*)(sM + row * 64 + seg * 16) = *(const uint4*)mb;
      } else {
        const int* mi = (const int*)maskp + (size_t)b * Tn * Tn + (size_t)(q0 + row) * Tn + k0 + seg * 16;
#pragma unroll
        for (int i2 = 0; i2 < 4; ++i2) {
          int4 qd = *(const int4*)(mi + 4 * i2);
          unsigned pk = (qd.x != 0 ? 1u : 0u) | (qd.y != 0 ? 0x100u : 0u) |
                        (qd.z != 0 ? 0x10000u : 0u) | (qd.w != 0 ? 0x1000000u : 0u);
          *(unsigned*)(sM + row * 64 + seg * 16 + 4 * i2) = pk;
        }
      }
      {
        int prow = t >> 1, pseg = t & 1;
        int gp = pbase + prow;
        if (gp > Pn - 1) gp = Pn - 1;  // row 127 is never consumed; clamp the read
        const unsigned short* src = Pb + ((size_t)h * Pn + gp) * DKn + pseg * 32;
        int psw = (prow & 7) << 4;
#pragma unroll
        for (int i2 = 0; i2 < 4; ++i2) {
          uint4 qd = *(const uint4*)(src + i2 * 8);
          int off = prow * 128 + pseg * 64 + i2 * 16;
          *(uint2*)(sP + ((off) ^ psw)) = make_uint2(qd.x, qd.y);
          *(uint2*)(sP + ((off + 8) ^ psw)) = make_uint2(qd.z, qd.w);
        }
      }
    }
    __syncthreads();

    // ---- AC and BD' MFMA ----
    f4 ac[4];
#pragma unroll
    for (int c = 0; c < 4; ++c) {
      ac[c] = {0.f, 0.f, 0.f, 0.f};
      int brow = 16 * c + lc;
      ac[c] = mfma16(au[0], frag_ld(sK, brow, 0, grp), ac[c]);
      ac[c] = mfma16(au[1], frag_ld(sK, brow, 1, grp), ac[c]);
    }
#pragma unroll
    for (int c = 0; c < 8; ++c) {
      f4 z = {0.f, 0.f, 0.f, 0.f};
      int brow = 16 * c + lc;
      z = mfma16(av[0], frag_ld(sP, brow, 0, grp), z);
      z = mfma16(av[1], frag_ld(sP, brow, 1, grp), z);
#pragma unroll
      for (int r = 0; r < 4; ++r)
        sBD[(16 * w + grp * 4 + r) * 129 + 16 * c + lc] = z[r];
    }
    __syncthreads();

    // ---- scores + online softmax ----
#pragma unroll
    for (int r = 0; r < 4; ++r) {
      const int row = 16 * w + grp * 4 + r;
      float sc[4];
      bool mk[4];
#pragma unroll
      for (int c = 0; c < 4; ++c) {
        int col = 16 * c + lc;
        // sBD[row*129 + (col-row+63)] == sBD[row*128 + col + 63]
        float vv = (ac[c][r] + sBD[row * 128 + col + 63]) * 0.125f;
        mk[c] = sM[row * 64 + col] != 0;
        sc[c] = mk[c] ? -10000.f : vv;
      }
      float mx = fmaxf(fmaxf(sc[0], sc[1]), fmaxf(sc[2], sc[3]));
#pragma unroll
      for (int d2 = 1; d2 < 16; d2 <<= 1) mx = fmaxf(mx, __shfl_xor(mx, d2, 64));
      float mnew = fmaxf(m_run[r], mx);
      float scl = __expf(m_run[r] - mnew);
      float ps = 0.f;
      unsigned short ph[4];
#pragma unroll
      for (int c = 0; c < 4; ++c) {
        float p = __expf(sc[c] - mnew);
        ps += p;
        ph[c] = f2h(mk[c] ? 0.f : p);  // zeroed for PV numerator, kept in denominator
      }
#pragma unroll
      for (int d2 = 1; d2 < 16; d2 <<= 1) ps += __shfl_xor(ps, d2, 64);
      l_run[r] = l_run[r] * scl + ps;
      m_run[r] = mnew;
#pragma unroll
      for (int c = 0; c < 4; ++c) oacc[c][r] *= scl;
      int sw = (row & 7) << 4;
#pragma unroll
      for (int c = 0; c < 4; ++c) {
        int off = row * 128 + (16 * c + lc) * 2;
        *(unsigned short*)(sPp + (off ^ sw)) = ph[c];
      }
    }
    __syncthreads();

    // ---- PV ----
    {
      const int prow_a = 16 * w + lc;
      h8 pa0 = frag_ld(sPp, prow_a, 0, grp);
      h8 pa1 = frag_ld(sPp, prow_a, 1, grp);
#pragma unroll
      for (int c = 0; c < 4; ++c) {
        int brow = 16 * c + lc;
        oacc[c] = mfma16(pa0, frag_ld(sV, brow, 0, grp), oacc[c]);
        oacc[c] = mfma16(pa1, frag_ld(sV, brow, 1, grp), oacc[c]);
      }
    }
  }

  // ---- epilogue: x[b][t][h*64+d] ----
#pragma unroll
  for (int c = 0; c < 4; ++c) {
#pragma unroll
    for (int r = 0; r < 4; ++r) {
      int rowq = 16 * w + grp * 4 + r;
      float vv = oacc[c][r] / l_run[r];
      size_t idx = ((size_t)b * Tn + q0 + rowq) * Fn + h * DKn + 16 * c + lc;
      xb[idx] = f2h(vv);
    }
  }
}

}  // namespace

extern "C" void kernel_launch(void* const* d_in, const int* in_sizes, int n_in,
                              void* d_out, int out_size, void* d_ws, size_t ws_size,
                              hipStream_t stream) {
  const float* query = (const float*)d_in[0];
  const float* key = (const float*)d_in[1];
  const float* value = (const float*)d_in[2];
  const void* maskp = d_in[3];
  const float* pos = (const float*)d_in[4];
  const float* Wq = (const float*)d_in[5];
  const float* bq = (const float*)d_in[6];
  const float* Wk = (const float*)d_in[7];
  const float* bk = (const float*)d_in[8];
  const float* Wv = (const float*)d_in[9];
  const float* bv = (const float*)d_in[10];
  const float* Wpos = (const float*)d_in[11];
  const float* Wo = (const float*)d_in[12];
  const float* bo = (const float*)d_in[13];
  const float* pu = (const float*)d_in[14];
  const float* pv = (const float*)d_in[15];
  float* out = (float*)d_out;

  unsigned char* ws = (unsigned char*)d_ws;
  int* flag = (int*)ws;
  const size_t nQKV = (size_t)Bn * Hn * Tn * DKn;  // 4194304 elems
  const size_t nP = (size_t)Hn * Pn * DKn;         // 1048064 elems
  unsigned short* Qu = (unsigned short*)(ws + 256);
  unsigned short* Qv = Qu + nQKV;
  unsigned short* Kb = Qv + nQKV;
  unsigned short* Vt = Kb + nQKV;
  unsigned short* Pbuf = Vt + nQKV;
  unsigned short* xb = Pbuf + nP;

  detect_kernel<<<dim3(1), dim3(64), 0, stream>>>((const unsigned int*)maskp, flag);
  proj_kernel<0><<<dim3(128, 8), dim3(256), 0, stream>>>(query, nullptr, Wq, bq, pu, pv, Qu, Qv, nullptr, Bn * Tn);
  proj_kernel<1><<<dim3(128, 8), dim3(256), 0, stream>>>(key, nullptr, Wk, bk, nullptr, nullptr, Kb, nullptr, nullptr, Bn * Tn);
  proj_kernel<2><<<dim3(128, 8), dim3(256), 0, stream>>>(value, nullptr, Wv, bv, nullptr, nullptr, Vt, nullptr, nullptr, Bn * Tn);
  proj_kernel<3><<<dim3(32, 8), dim3(256), 0, stream>>>(pos, nullptr, Wpos, nullptr, nullptr, nullptr, Pbuf, nullptr, nullptr, Pn);
  attn_kernel<<<dim3(16, 64), dim3(256), 0, stream>>>(Qu, Qv, Kb, Vt, Pbuf, maskp, flag, xb);
  proj_kernel<4><<<dim3(128, 8), dim3(256), 0, stream>>>(nullptr, xb, Wo, bo, nullptr, nullptr, nullptr, nullptr, out, Bn * Tn);
}